// Round 5
// baseline (2570.658 us; speedup 1.0000x reference)
//
#include <hip/hip_runtime.h>
#include <hip/hip_fp16.h>

// LSTM: B=32, T=512, D=1024, H=1024.
// Pipeline: wtrans (Wx->Wt fp16 T) ; xcvt (X->fp16) ; proj (fp16 MFMA) ;
//           persistent recurrent kernel: 64 blocks x 512 thr, 16 h-cols/block,
//           fp16 MFMA, flat 64-flag grid barrier, sc0/sc1 coherent h traffic.

typedef __attribute__((ext_vector_type(8))) _Float16 f16x8;
typedef __attribute__((ext_vector_type(8))) short    short8;
typedef __attribute__((ext_vector_type(4))) float    f32x4;

__device__ __forceinline__ float sigm_f(float x) { return 1.0f / (1.0f + __expf(-x)); }
__device__ __forceinline__ float tanh_f(float x) { return 1.0f - 2.0f / (__expf(2.0f * x) + 1.0f); }

__device__ __forceinline__ void ld_sys_b128(short8& d, const void* p) {
    asm volatile("global_load_dwordx4 %0, %1, off sc0 sc1" : "=v"(d) : "v"(p) : "memory");
}
__device__ __forceinline__ void st_sys_u16(void* p, unsigned v) {
    asm volatile("global_store_short %0, %1, off sc0 sc1" :: "v"(p), "v"(v) : "memory");
}

// ---------------- X -> fp16 ----------------
__global__ __launch_bounds__(256)
void xcvt_kernel(const float* __restrict__ X, unsigned short* __restrict__ Xh)
{
    int i = blockIdx.x * 256 + threadIdx.x;          // oct id, 2,097,152 total
    float4 v0 = *reinterpret_cast<const float4*>(X + (size_t)i * 8);
    float4 v1 = *reinterpret_cast<const float4*>(X + (size_t)i * 8 + 4);
    unsigned short o[8];
    o[0] = __half_as_ushort(__float2half_rn(v0.x));
    o[1] = __half_as_ushort(__float2half_rn(v0.y));
    o[2] = __half_as_ushort(__float2half_rn(v0.z));
    o[3] = __half_as_ushort(__float2half_rn(v0.w));
    o[4] = __half_as_ushort(__float2half_rn(v1.x));
    o[5] = __half_as_ushort(__float2half_rn(v1.y));
    o[6] = __half_as_ushort(__float2half_rn(v1.z));
    o[7] = __half_as_ushort(__float2half_rn(v1.w));
    *reinterpret_cast<int4*>(Xh + (size_t)i * 8) = *reinterpret_cast<int4*>(o);
}

// ---------------- W transpose + fp16 convert (validated round 4) ----------------
__global__ __launch_bounds__(256)
void wtrans_kernel(const float* __restrict__ Wa, const float* __restrict__ Wi,
                   const float* __restrict__ Wf, const float* __restrict__ Wo,
                   unsigned short* __restrict__ Wt)
{
    __shared__ float Ts[64][65];
    const int bx = blockIdx.x;
    const int g  = bx >> 8;
    const int k0 = ((bx >> 4) & 15) * 64;
    const int c0 = (bx & 15) * 64;
    const float* W = (g == 0) ? Wa : ((g == 1) ? Wi : ((g == 2) ? Wf : Wo));
    const int tid = threadIdx.x;
#pragma unroll
    for (int u = 0; u < 4; ++u) {
        int r  = u * 16 + (tid >> 4);
        int c4 = (tid & 15) * 4;
        float4 v = *reinterpret_cast<const float4*>(W + (size_t)(k0 + r) * 1024 + c0 + c4);
        Ts[r][c4 + 0] = v.x; Ts[r][c4 + 1] = v.y; Ts[r][c4 + 2] = v.z; Ts[r][c4 + 3] = v.w;
    }
    __syncthreads();
#pragma unroll
    for (int u = 0; u < 4; ++u) {
        int col = u * 16 + (tid >> 4);
        int k4  = (tid & 15) * 4;
        unsigned short o[4];
#pragma unroll
        for (int j = 0; j < 4; ++j)
            o[j] = __half_as_ushort(__float2half_rn(Ts[k4 + j][col]));
        *reinterpret_cast<ushort4*>(Wt + ((size_t)g * 1024 + c0 + col) * 1024 + k0 + k4) =
            *reinterpret_cast<ushort4*>(o);
    }
}

// ---------------- Projection GEMM via fp16 MFMA (A now fp16) ----------------
__global__ __launch_bounds__(256)
void proj_mfma(const _Float16* __restrict__ Xh,
               const _Float16* __restrict__ Wt,
               unsigned short* __restrict__ xg)
{
    __shared__ _Float16 As[128 * 40];
    __shared__ _Float16 Bs[128 * 40];

    const int tid  = threadIdx.x;
    const int bn   = blockIdx.x & 31;
    const int bm   = blockIdx.x >> 5;
    const int row0 = bm * 128, col0 = bn * 128;
    const int w    = tid >> 6, lane = tid & 63;
    const int wm   = w >> 1,  wn   = w & 1;
    const int lr   = lane & 15, ko = lane >> 4;

    f32x4 acc[4][4];
#pragma unroll
    for (int mi = 0; mi < 4; ++mi)
#pragma unroll
        for (int ni = 0; ni < 4; ++ni)
            acc[mi][ni] = f32x4{0.f, 0.f, 0.f, 0.f};

    for (int kt = 0; kt < 1024; kt += 32) {
#pragma unroll
        for (int u = 0; u < 2; ++u) {
            int i8  = u * 256 + tid;
            int r   = i8 >> 2, k8 = (i8 & 3) * 8;
            *reinterpret_cast<float4*>(&As[r * 40 + k8]) =
                *reinterpret_cast<const float4*>(Xh + (size_t)(row0 + r) * 1024 + kt + k8);
        }
#pragma unroll
        for (int u = 0; u < 2; ++u) {
            int i8  = u * 256 + tid;
            int col = i8 >> 2, k8 = (i8 & 3) * 8;
            *reinterpret_cast<float4*>(&Bs[col * 40 + k8]) =
                *reinterpret_cast<const float4*>(Wt + (size_t)(col0 + col) * 1024 + kt + k8);
        }
        __syncthreads();

        f16x8 af[4], bf[4];
#pragma unroll
        for (int mi = 0; mi < 4; ++mi)
            af[mi] = *reinterpret_cast<const f16x8*>(&As[(wm * 64 + mi * 16 + lr) * 40 + ko * 8]);
#pragma unroll
        for (int ni = 0; ni < 4; ++ni)
            bf[ni] = *reinterpret_cast<const f16x8*>(&Bs[(wn * 64 + ni * 16 + lr) * 40 + ko * 8]);
#pragma unroll
        for (int mi = 0; mi < 4; ++mi)
#pragma unroll
            for (int ni = 0; ni < 4; ++ni)
                acc[mi][ni] = __builtin_amdgcn_mfma_f32_16x16x32_f16(af[mi], bf[ni], acc[mi][ni], 0, 0, 0);
        __syncthreads();
    }

#pragma unroll
    for (int mi = 0; mi < 4; ++mi)
#pragma unroll
        for (int ni = 0; ni < 4; ++ni)
#pragma unroll
            for (int j = 0; j < 4; ++j) {
                int rt = row0 + wm * 64 + mi * 16 + ko * 4 + j;
                int ct = col0 + wn * 64 + ni * 16 + lr;
                int b = rt >> 9, t = rt & 511;
                xg[((size_t)t * 32 + b) * 4096 + ct] =
                    __half_as_ushort(__float2half_rn(acc[mi][ni][j]));
            }
}

// ---------------- Persistent MFMA recurrent kernel: 64 blocks ----------------
// Block owns h-cols [blk*16, blk*16+16) -> 64 gate-cols (4 gates x 16).
// 8 waves, K-split 8: wave wv does kit in [wv*4, wv*4+4), 2 M-tiles x 4 N-tiles
// (N-tile n == gate g). 8-way partial reduce via pbuf (f32x4), gbuf pad-17.
__global__ __launch_bounds__(512)
void lstm_persist64(const unsigned short* __restrict__ xg,   // [512][32][4096] fp16
                    const float* __restrict__ Wah, const float* __restrict__ Wih,
                    const float* __restrict__ Wfh, const float* __restrict__ Woh,
                    const float* __restrict__ ba, const float* __restrict__ bi,
                    const float* __restrict__ bfv, const float* __restrict__ bo,
                    unsigned short* __restrict__ wpk,        // [64][65536] fp16 B-frag order
                    unsigned short* __restrict__ h16A,       // [128][32][8] fp16
                    unsigned short* __restrict__ h16B,
                    unsigned* __restrict__ flags,            // [64] pre-zeroed
                    float* __restrict__ out)                 // [32][512][1024]
{
    __shared__ float pbuf[8 * 2048];                 // [wv][((m*4+n)*64+lane)*4+reg]
    __shared__ float gbuf[32 * 4 * 17];              // [(row*4+g)*17+hc]
    __shared__ unsigned short xbuf[32 * 64];         // [row][g*16+hc]

    const int tid  = threadIdx.x;
    const int blk  = blockIdx.x;
    const int hcol0 = blk * 16;
    const int wv   = tid >> 6;
    const int lane = tid & 63;

    // ---- pack Wh slice into B-frag order (once) ----
    // wb[fq*8+e], fq = (kit*4+n)*64+ln: = f16(W_n[kit*32+(ln>>4)*8+e][hcol0+(ln&15)])
    unsigned short* wb = wpk + (size_t)blk * 65536;
#pragma unroll
    for (int u = 0; u < 16; ++u) {
        int fq  = u * 512 + tid;                     // 0..8191
        int kit = fq >> 8;
        int n   = (fq >> 6) & 3;
        int ln  = fq & 63;
        int kbase = kit * 32 + (ln >> 4) * 8;
        int col   = hcol0 + (ln & 15);
        const float* Wg = (n == 0) ? Wah : ((n == 1) ? Wih : ((n == 2) ? Wfh : Woh));
        unsigned short tmp[8];
#pragma unroll
        for (int e = 0; e < 8; ++e)
            tmp[e] = __half_as_ushort(__float2half_rn(Wg[(size_t)(kbase + e) * 1024 + col]));
        *reinterpret_cast<int4*>(wb + (size_t)fq * 8) = *reinterpret_cast<int4*>(tmp);
    }

    // gate mapping: every thread owns one (row, hc) output
    const int row = tid >> 4;                        // 0..31
    const int hc  = tid & 15;                        // 0..15
    const float bias_a = ba [hcol0 + hc];
    const float bias_i = bi [hcol0 + hc];
    const float bias_f = bfv[hcol0 + hc];
    const float bias_o = bo [hcol0 + hc];
    float sreg = 0.f;

    __syncthreads();

    const int koct = lane >> 4;
    const int arow = lane & 15;

    for (int t = 0; t < 512; ++t) {
        if (t > 0) {
            __syncthreads();                         // drain h sc-stores (vmcnt0/wave)
            if (tid == 0)
                __hip_atomic_store(&flags[blk], (unsigned)t, __ATOMIC_RELAXED, __HIP_MEMORY_SCOPE_AGENT);
            if (tid >= 64 && tid < 192) {            // stage xg tile during poll
#pragma unroll
                for (int j = 0; j < 4; ++j) {
                    int q  = (tid - 64) * 4 + j;     // 0..511
                    int r  = q >> 4, c4 = (q & 15) * 4;
                    int g  = c4 >> 4, hq = c4 & 15;
                    ushort4 v = *reinterpret_cast<const ushort4*>(
                        xg + ((size_t)t * 32 + r) * 4096 + g * 1024 + hcol0 + hq);
                    *reinterpret_cast<ushort4*>(&xbuf[r * 64 + c4]) = v;
                }
            }
            if (tid < 64) {
                for (;;) {
                    unsigned v = __hip_atomic_load(&flags[tid], __ATOMIC_RELAXED, __HIP_MEMORY_SCOPE_AGENT);
                    if (__all(v >= (unsigned)t)) break;
                    __builtin_amdgcn_s_sleep(1);
                }
            }
            __syncthreads();
        } else {
            int q = tid;
            int r = q >> 4, c4 = (q & 15) * 4;
            int g = c4 >> 4, hq = c4 & 15;
            ushort4 v = *reinterpret_cast<const ushort4*>(
                xg + ((size_t)r * 4096) + g * 1024 + hcol0 + hq);
            *reinterpret_cast<ushort4*>(&xbuf[r * 64 + c4]) = v;
            __syncthreads();
        }

        const unsigned short* hp = (t & 1) ? h16A : h16B;
        unsigned short*       hn = (t & 1) ? h16B : h16A;

        if (t > 0) {
            short8 a0[4], a1[4], b[4][4];
#pragma unroll
            for (int ki = 0; ki < 4; ++ki) {
                int kit = wv * 4 + ki;
#pragma unroll
                for (int n = 0; n < 4; ++n)
                    b[ki][n] = *reinterpret_cast<const short8*>(wb + ((size_t)((kit * 4 + n) * 64 + lane) * 8));
            }
#pragma unroll
            for (int ki = 0; ki < 4; ++ki) {
                int kit = wv * 4 + ki;
                int oct = kit * 4 + koct;
                ld_sys_b128(a0[ki], hp + ((size_t)(oct * 32 + arow) * 8));
                ld_sys_b128(a1[ki], hp + ((size_t)(oct * 32 + arow + 16) * 8));
            }
            asm volatile("s_waitcnt vmcnt(0)" ::: "memory");
            __builtin_amdgcn_sched_barrier(0);

            f32x4 acc[2][4];
#pragma unroll
            for (int m = 0; m < 2; ++m)
#pragma unroll
                for (int n = 0; n < 4; ++n)
                    acc[m][n] = f32x4{0.f, 0.f, 0.f, 0.f};
#pragma unroll
            for (int ki = 0; ki < 4; ++ki) {
#pragma unroll
                for (int n = 0; n < 4; ++n) {
                    acc[0][n] = __builtin_amdgcn_mfma_f32_16x16x32_f16(
                        __builtin_bit_cast(f16x8, a0[ki]), __builtin_bit_cast(f16x8, b[ki][n]), acc[0][n], 0, 0, 0);
                    acc[1][n] = __builtin_amdgcn_mfma_f32_16x16x32_f16(
                        __builtin_bit_cast(f16x8, a1[ki]), __builtin_bit_cast(f16x8, b[ki][n]), acc[1][n], 0, 0, 0);
                }
            }
#pragma unroll
            for (int m = 0; m < 2; ++m)
#pragma unroll
                for (int n = 0; n < 4; ++n)
                    *reinterpret_cast<f32x4*>(&pbuf[wv * 2048 + ((m * 4 + n) * 64 + lane) * 4]) = acc[m][n];
        }
        __syncthreads();

        if (t > 0) {
            // 8-way reduce: thread tid sums f32x4 at flat = tid*4
            f32x4 s4 = f32x4{0.f, 0.f, 0.f, 0.f};
#pragma unroll
            for (int w = 0; w < 8; ++w)
                s4 += *reinterpret_cast<const f32x4*>(&pbuf[w * 2048 + tid * 4]);
            int ln2 = tid & 63;
            int n2  = (tid >> 6) & 3;
            int m2  = tid >> 8;
            int hh  = ln2 & 15;
            int rhi = m2 * 16 + (ln2 >> 4) * 4;
#pragma unroll
            for (int rg = 0; rg < 4; ++rg)
                gbuf[((rhi + rg) * 4 + n2) * 17 + hh] = s4[rg];
        }
        __syncthreads();

        {
            float ga = (t > 0 ? gbuf[(row * 4 + 0) * 17 + hc] : 0.f) + bias_a
                     + __half2float(__ushort_as_half(xbuf[row * 64 + 0 * 16 + hc]));
            float gi = (t > 0 ? gbuf[(row * 4 + 1) * 17 + hc] : 0.f) + bias_i
                     + __half2float(__ushort_as_half(xbuf[row * 64 + 1 * 16 + hc]));
            float gf = (t > 0 ? gbuf[(row * 4 + 2) * 17 + hc] : 0.f) + bias_f
                     + __half2float(__ushort_as_half(xbuf[row * 64 + 2 * 16 + hc]));
            float gO = (t > 0 ? gbuf[(row * 4 + 3) * 17 + hc] : 0.f) + bias_o
                     + __half2float(__ushort_as_half(xbuf[row * 64 + 3 * 16 + hc]));
            float a  = tanh_f(ga);
            float ii = sigm_f(gi);
            float ff = sigm_f(gf);
            float oo = sigm_f(gO);
            sreg = a * ii + sreg * ff;
            float hv = tanh_f(sreg) * oo;

            int colg = hcol0 + hc;
            out[((size_t)row * 512 + t) * 1024 + colg] = hv;
            st_sys_u16(hn + ((size_t)(colg >> 3) * 32 + row) * 8 + (colg & 7),
                       (unsigned)__half_as_ushort(__float2half_rn(hv)));
        }
    }
}

// ---------------- Fallback per-step kernel (round-1 FUSED, fp32) ----------------
template<bool FIRST>
__global__ __launch_bounds__(256)
void step_kernel(const float* __restrict__ hprev, float* __restrict__ hnext,
                 float* __restrict__ sbuf, const float* __restrict__ X,
                 const float* __restrict__ Wah, const float* __restrict__ Wih,
                 const float* __restrict__ Wfh, const float* __restrict__ Woh,
                 const float* __restrict__ Wax, const float* __restrict__ Wix,
                 const float* __restrict__ Wfx, const float* __restrict__ Wox,
                 const float* __restrict__ ba, const float* __restrict__ bi,
                 const float* __restrict__ bfv, const float* __restrict__ bo,
                 float* __restrict__ out, int t)
{
    __shared__ float hs[32 * 1028];
    __shared__ float gs[2][32][16];

    const int tid  = threadIdx.x;
    const int hc0  = blockIdx.x * 4;
    const int kh   = tid >> 7;
    const int gtid = tid & 127;
    const int r    = gtid >> 2;
    const int gate = gtid & 3;
    const int k0   = kh * 512;

    float4 acc = make_float4(0.f, 0.f, 0.f, 0.f);

    if (!FIRST) {
        for (int u = 0; u < 32; u++) {
            int f4 = u * 256 + tid;
            int rr = f4 >> 8;
            int kq = (f4 & 255) << 2;
            *reinterpret_cast<float4*>(&hs[rr * 1028 + kq]) =
                *reinterpret_cast<const float4*>(hprev + rr * 1024 + kq);
        }
        __syncthreads();
        const float* Wg = (gate == 0) ? Wah : ((gate == 1) ? Wih : ((gate == 2) ? Wfh : Woh));
        const float* Wp = Wg + hc0;
#pragma unroll 4
        for (int k = k0; k < k0 + 512; k += 4) {
            float4 hv = *reinterpret_cast<const float4*>(&hs[r * 1028 + k]);
            float4 w0 = *reinterpret_cast<const float4*>(Wp + (size_t)(k + 0) * 1024);
            float4 w1 = *reinterpret_cast<const float4*>(Wp + (size_t)(k + 1) * 1024);
            float4 w2 = *reinterpret_cast<const float4*>(Wp + (size_t)(k + 2) * 1024);
            float4 w3 = *reinterpret_cast<const float4*>(Wp + (size_t)(k + 3) * 1024);
            acc.x += hv.x * w0.x + hv.y * w1.x + hv.z * w2.x + hv.w * w3.x;
            acc.y += hv.x * w0.y + hv.y * w1.y + hv.z * w2.y + hv.w * w3.y;
            acc.z += hv.x * w0.z + hv.y * w1.z + hv.z * w2.z + hv.w * w3.z;
            acc.w += hv.x * w0.w + hv.y * w1.w + hv.z * w2.w + hv.w * w3.w;
        }
    }
    {
        __syncthreads();
        for (int u = 0; u < 32; u++) {
            int f4 = u * 256 + tid;
            int rr = f4 >> 8;
            int kq = (f4 & 255) << 2;
            *reinterpret_cast<float4*>(&hs[rr * 1028 + kq]) =
                *reinterpret_cast<const float4*>(X + ((size_t)rr * 512 + t) * 1024 + kq);
        }
        __syncthreads();
        const float* Wg = (gate == 0) ? Wax : ((gate == 1) ? Wix : ((gate == 2) ? Wfx : Wox));
        const float* Wp = Wg + hc0;
#pragma unroll 4
        for (int k = k0; k < k0 + 512; k += 4) {
            float4 hv = *reinterpret_cast<const float4*>(&hs[r * 1028 + k]);
            float4 w0 = *reinterpret_cast<const float4*>(Wp + (size_t)(k + 0) * 1024);
            float4 w1 = *reinterpret_cast<const float4*>(Wp + (size_t)(k + 1) * 1024);
            float4 w2 = *reinterpret_cast<const float4*>(Wp + (size_t)(k + 2) * 1024);
            float4 w3 = *reinterpret_cast<const float4*>(Wp + (size_t)(k + 3) * 1024);
            acc.x += hv.x * w0.x + hv.y * w1.x + hv.z * w2.x + hv.w * w3.x;
            acc.y += hv.x * w0.y + hv.y * w1.y + hv.z * w2.y + hv.w * w3.y;
            acc.z += hv.x * w0.z + hv.y * w1.z + hv.z * w2.z + hv.w * w3.z;
            acc.w += hv.x * w0.w + hv.y * w1.w + hv.z * w2.w + hv.w * w3.w;
        }
    }

    *reinterpret_cast<float4*>(&gs[kh][r][gate * 4]) = acc;
    __syncthreads();

    if (tid < 128) {
        const int rr = tid >> 2;
        const int hcl = tid & 3;
        const int h  = hc0 + hcl;
        float ga = gs[0][rr][0 + hcl]  + gs[1][rr][0 + hcl]  + ba[h];
        float gi = gs[0][rr][4 + hcl]  + gs[1][rr][4 + hcl]  + bi[h];
        float gf = gs[0][rr][8 + hcl]  + gs[1][rr][8 + hcl]  + bfv[h];
        float gO = gs[0][rr][12 + hcl] + gs[1][rr][12 + hcl] + bo[h];
        float a = tanh_f(ga);
        float i = sigm_f(gi);
        float f = sigm_f(gf);
        float o = sigm_f(gO);
        float sprev = FIRST ? 0.f : sbuf[rr * 1024 + h];
        float s = a * i + sprev * f;
        sbuf[rr * 1024 + h] = s;
        float hv = tanh_f(s) * o;
        hnext[rr * 1024 + h] = hv;
        out[((size_t)rr * 512 + t) * 1024 + h] = hv;
    }
}

extern "C" void kernel_launch(void* const* d_in, const int* in_sizes, int n_in,
                              void* d_out, int out_size, void* d_ws, size_t ws_size,
                              hipStream_t stream)
{
    const float* X   = (const float*)d_in[0];
    const float* Wax = (const float*)d_in[1];
    const float* Wix = (const float*)d_in[2];
    const float* Wfx = (const float*)d_in[3];
    const float* Wox = (const float*)d_in[4];
    const float* Wah = (const float*)d_in[5];
    const float* Wih = (const float*)d_in[6];
    const float* Wfh = (const float*)d_in[7];
    const float* Woh = (const float*)d_in[8];
    const float* ba  = (const float*)d_in[9];
    const float* bi  = (const float*)d_in[10];
    const float* bfv = (const float*)d_in[11];
    const float* bo  = (const float*)d_in[12];
    float* out = (float*)d_out;

    const size_t XGH  = (size_t)512 * 32 * 4096 * 2;      // 128 MiB fp16 xg
    const size_t WPK  = (size_t)64 * 65536 * 2;           // 8 MiB fp16 packed Wh
    const size_t WTX  = (size_t)4096 * 1024 * 2;          // 8 MiB fp16 Wt
    const size_t XHH  = (size_t)16384 * 1024 * 2;         // 32 MiB fp16 Xh
    const size_t H16  = (size_t)32 * 1024 * 2;            // 64 KiB fp16 h
    const size_t BAR  = 4096;
    const size_t HBF  = (size_t)32 * 1024 * 4;

    char* ws = (char*)d_ws;
    const bool big = ws_size >= XGH + WPK + WTX + XHH + 2 * H16 + BAR;

    if (big) {
        unsigned short* xg    = (unsigned short*)ws;
        unsigned short* wpk   = (unsigned short*)(ws + XGH);
        unsigned short* Wt    = (unsigned short*)(ws + XGH + WPK);
        unsigned short* Xh    = (unsigned short*)(ws + XGH + WPK + WTX);
        unsigned short* h16A  = (unsigned short*)(ws + XGH + WPK + WTX + XHH);
        unsigned short* h16B  = (unsigned short*)(ws + XGH + WPK + WTX + XHH + H16);
        unsigned*       flags = (unsigned*)(ws + XGH + WPK + WTX + XHH + 2 * H16);

        hipMemsetAsync(flags, 0, BAR, stream);
        wtrans_kernel<<<1024, 256, 0, stream>>>(Wax, Wix, Wfx, Wox, Wt);
        xcvt_kernel<<<8192, 256, 0, stream>>>(X, Xh);
        proj_mfma<<<4096, 256, 0, stream>>>((const _Float16*)Xh, (const _Float16*)Wt, xg);

        const unsigned short* xgu = xg;
        void* args[] = {
            (void*)&xgu,
            (void*)&Wah, (void*)&Wih, (void*)&Wfh, (void*)&Woh,
            (void*)&ba, (void*)&bi, (void*)&bfv, (void*)&bo,
            (void*)&wpk, (void*)&h16A, (void*)&h16B,
            (void*)&flags, (void*)&out
        };
        hipLaunchCooperativeKernel((void*)lstm_persist64, dim3(64), dim3(512),
                                   args, 0, stream);
    } else {
        float* h0 = (float*)ws;
        float* h1 = (float*)(ws + HBF);
        float* sb = (float*)(ws + 2 * HBF);
        float* hb[2] = { h0, h1 };
        for (int t = 0; t < 512; ++t) {
            const float* hprev = hb[(t + 1) & 1];
            float* hnext = hb[t & 1];
            if (t == 0)
                step_kernel<true><<<256, 256, 0, stream>>>(hprev, hnext, sb, X,
                    Wah, Wih, Wfh, Woh, Wax, Wix, Wfx, Wox, ba, bi, bfv, bo, out, t);
            else
                step_kernel<false><<<256, 256, 0, stream>>>(hprev, hnext, sb, X,
                    Wah, Wih, Wfh, Woh, Wax, Wix, Wfx, Wox, ba, bi, bfv, bo, out, t);
        }
    }
}